// Round 1
// baseline (353.124 us; speedup 1.0000x reference)
//
#include <hip/hip_runtime.h>

// Survival cross-entropy loss, N=1e6 rows x T=64 bins.
// loss_i = event ? -(csum_{j<t} lg_j) - log(h_t) : -(csum_{j<=t} lg_j)
// with h = clamp(pred, 1e-9, 1-1e-9), lg = log1p(-h).
// Rewritten as independent per-element contributions (no row reduction):
//   c_ij = (j<=t ? -lg_ij : 0) + (event && j==t ? lg_ij - log(h_ij) : 0)
// Accumulate in log2 space; scale by ln2 once per lane at the end.

#ifndef T_BINS
#define T_BINS 64
#endif

__global__ __launch_bounds__(256) void cesl_kernel(
    const float* __restrict__ preds,
    const int* __restrict__ targets,
    float* __restrict__ out,
    int n_rows)
{
    const int lane         = threadIdx.x & 63;
    const int waveInBlock  = threadIdx.x >> 6;
    const int wavesPerBlk  = blockDim.x >> 6;
    const int globalWave   = blockIdx.x * wavesPerBlk + waveInBlock;
    const int totalWaves   = gridDim.x * wavesPerBlk;

    // Layout: 16 lanes per row, 4 consecutive cols per lane -> one
    // dwordx4 load per lane covers 4 rows per wave-iteration (1 KB/wave).
    const int group   = lane >> 4;         // which of the 4 rows in this chunk
    const int colBase = (lane & 15) * 4;   // starting column for this lane

    float acc = 0.0f;  // log2 space

    const int nChunks = n_rows >> 2;
    for (int chunk = globalWave; chunk < nChunks; chunk += totalWaves) {
        const int row = chunk * 4 + group;
        const float4 p4 = *reinterpret_cast<const float4*>(
            preds + (size_t)row * T_BINS + colBase);
        const int2 tg = *reinterpret_cast<const int2*>(targets + (size_t)row * 2);
        int t = tg.x;
        t = (t < 0) ? 0 : (t > T_BINS - 1 ? T_BINS - 1 : t);
        const bool ev = (tg.y != 0);

        const float p[4] = {p4.x, p4.y, p4.z, p4.w};
#pragma unroll
        for (int k = 0; k < 4; ++k) {
            const int col = colBase + k;
            float h = fmaxf(p[k], 1e-9f);
            h = fminf(h, 0.99999994f);     // fp32 nextbelow(1): avoids log(0)
            const float l = __log2f(1.0f - h);
            float c = (col <= t) ? -l : 0.0f;
            if (ev && col == t) c += l - __log2f(h);
            acc += c;
        }
    }

    // tail rows (n_rows % 4) — no-op for N=1e6
    const int tailStart = nChunks * 4;
    if (globalWave == 0 && tailStart < n_rows) {
        // lanes 0..15 of wave 0 process remaining rows serially per row
        for (int row = tailStart + group; row < n_rows; row += 4) {
            const float4 p4 = *reinterpret_cast<const float4*>(
                preds + (size_t)row * T_BINS + colBase);
            const int2 tg = *reinterpret_cast<const int2*>(targets + (size_t)row * 2);
            int t = tg.x;
            t = (t < 0) ? 0 : (t > T_BINS - 1 ? T_BINS - 1 : t);
            const bool ev = (tg.y != 0);
            const float p[4] = {p4.x, p4.y, p4.z, p4.w};
#pragma unroll
            for (int k = 0; k < 4; ++k) {
                const int col = colBase + k;
                float h = fmaxf(p[k], 1e-9f);
                h = fminf(h, 0.99999994f);
                const float l = __log2f(1.0f - h);
                float c = (col <= t) ? -l : 0.0f;
                if (ev && col == t) c += l - __log2f(h);
                acc += c;
            }
        }
    }

    acc *= 0.69314718055994530942f;  // ln(2): log2 -> ln

    // wave reduction (64 lanes)
#pragma unroll
    for (int off = 32; off > 0; off >>= 1)
        acc += __shfl_xor(acc, off, 64);

    __shared__ float waveSums[8];
    if (lane == 0) waveSums[waveInBlock] = acc;
    __syncthreads();
    if (threadIdx.x == 0) {
        float s = 0.0f;
        for (int w = 0; w < wavesPerBlk; ++w) s += waveSums[w];
        atomicAdd(out, s * (1.0f / (float)n_rows));
    }
}

extern "C" void kernel_launch(void* const* d_in, const int* in_sizes, int n_in,
                              void* d_out, int out_size, void* d_ws, size_t ws_size,
                              hipStream_t stream) {
    const float* preds  = (const float*)d_in[0];
    const int* targets  = (const int*)d_in[1];
    float* out          = (float*)d_out;
    const int n_rows    = in_sizes[0] / T_BINS;

    hipMemsetAsync(d_out, 0, sizeof(float), stream);

    const int blocks = 2048;   // 8 blocks/CU, 32 waves/CU; ~30 iters/wave
    cesl_kernel<<<blocks, 256, 0, stream>>>(preds, targets, out, n_rows);
}

// Round 3
// 345.617 us; speedup vs baseline: 1.0217x; 1.0217x over previous
//
#include <hip/hip_runtime.h>

// Survival cross-entropy loss, N=1e6 rows x T=64 bins.
// Per-element decomposition (no cumsum, no row reduction):
//   col <  t : contributes -log(1-h)
//   col == t : contributes -log(h) if event else -log(1-h)
//   col >  t : contributes 0
// Single log per element: arg = col>t ? 1.0 : (col==t && ev ? h : 1-h);
// elem = -log(arg); log(1.0)==0 makes the col>t case free.
// Accumulate +log2(arg); scale by -ln2/n once at the end.

#ifndef T_BINS
#define T_BINS 64
#endif

// native vector type: __builtin_nontemporal_load needs this, not HIP_vector_type
typedef float floatx4 __attribute__((ext_vector_type(4)));

__global__ __launch_bounds__(256) void cesl_kernel(
    const float* __restrict__ preds,
    const int* __restrict__ targets,
    float* __restrict__ out,
    int n_rows)
{
    const int lane        = threadIdx.x & 63;
    const int waveInBlock = threadIdx.x >> 6;
    const int wavesPerBlk = blockDim.x >> 6;
    const int globalWave  = blockIdx.x * wavesPerBlk + waveInBlock;
    const int totalWaves  = gridDim.x * wavesPerBlk;

    // 16 lanes per row, 4 consecutive cols per lane: one dwordx4/lane,
    // 64 lanes cover 4 contiguous rows = 1 KB coalesced per wave-iter.
    const int group   = lane >> 4;         // row within the 4-row chunk
    const int colBase = (lane & 15) * 4;   // starting column for this lane

    float acc = 0.0f;  // sum of log2(arg); loss = -ln2 * acc

    const int nChunks = n_rows >> 2;
    for (int chunk = globalWave; chunk < nChunks; chunk += totalWaves) {
        const int row = chunk * 4 + group;
        const floatx4 p4 = __builtin_nontemporal_load(
            reinterpret_cast<const floatx4*>(preds + (size_t)row * T_BINS + colBase));
        const int2 tg = *reinterpret_cast<const int2*>(targets + (size_t)row * 2);
        int t = tg.x;
        t = (t < 0) ? 0 : (t > T_BINS - 1 ? T_BINS - 1 : t);
        const bool ev = (tg.y != 0);

#pragma unroll
        for (int k = 0; k < 4; ++k) {
            const int col = colBase + k;
            const float h = fminf(fmaxf(p4[k], 1e-9f), 0.99999994f);
            float arg = 1.0f - h;
            arg = (ev && col == t) ? h : arg;      // event at target bin: h
            arg = (col > t) ? 1.0f : arg;          // past target: log(1)=0
            acc += __log2f(arg);
        }
    }

    // tail rows (n_rows % 4) — empty for N=1e6
    const int tailStart = nChunks * 4;
    if (globalWave == 0 && tailStart < n_rows) {
        for (int row = tailStart + group; row < n_rows; row += 4) {
            const floatx4 p4 = *reinterpret_cast<const floatx4*>(
                preds + (size_t)row * T_BINS + colBase);
            const int2 tg = *reinterpret_cast<const int2*>(targets + (size_t)row * 2);
            int t = tg.x;
            t = (t < 0) ? 0 : (t > T_BINS - 1 ? T_BINS - 1 : t);
            const bool ev = (tg.y != 0);
#pragma unroll
            for (int k = 0; k < 4; ++k) {
                const int col = colBase + k;
                const float h = fminf(fmaxf(p4[k], 1e-9f), 0.99999994f);
                float arg = 1.0f - h;
                arg = (ev && col == t) ? h : arg;
                arg = (col > t) ? 1.0f : arg;
                acc += __log2f(arg);
            }
        }
    }

    // wave reduction (64 lanes)
#pragma unroll
    for (int off = 32; off > 0; off >>= 1)
        acc += __shfl_xor(acc, off, 64);

    __shared__ float waveSums[8];
    if (lane == 0) waveSums[waveInBlock] = acc;
    __syncthreads();
    if (threadIdx.x == 0) {
        float s = 0.0f;
        for (int w = 0; w < wavesPerBlk; ++w) s += waveSums[w];
        // loss = -ln2 * sum(log2(arg)) / n
        atomicAdd(out, s * (-0.69314718055994530942f / (float)n_rows));
    }
}

extern "C" void kernel_launch(void* const* d_in, const int* in_sizes, int n_in,
                              void* d_out, int out_size, void* d_ws, size_t ws_size,
                              hipStream_t stream) {
    const float* preds  = (const float*)d_in[0];
    const int* targets  = (const int*)d_in[1];
    float* out          = (float*)d_out;
    const int n_rows    = in_sizes[0] / T_BINS;

    (void)hipMemsetAsync(d_out, 0, sizeof(float), stream);

    const int blocks = 2048;   // 8 blocks/CU x 256 thr -> 32 waves/CU
    cesl_kernel<<<blocks, 256, 0, stream>>>(preds, targets, out, n_rows);
}

// Round 4
// 345.298 us; speedup vs baseline: 1.0227x; 1.0009x over previous
//
#include <hip/hip_runtime.h>

// Survival cross-entropy loss, N=1e6 rows x T=64 bins.
// Per-element decomposition (no cumsum, no row reduction):
//   col <  t : contributes -log(1-h)
//   col == t : contributes -log(h) if event else -log(1-h)
//   col >  t : contributes 0
// Columns j > t contribute nothing -> lanes whose 4-col chunk lies fully
// past t SKIP THE LOAD (masked lanes issue no memory requests; average
// row fetch drops from 256 B to ~160 B at 64 B granularity, t~U[0,64)).
// The 4 selected args are multiplied and a single log2 taken per lane-iter
// (args in [6e-8,1], product >= 1.2e-29 -- safely normal fp32).
// Accumulate +log2(prod); scale by -ln2/n once at the end.

#ifndef T_BINS
#define T_BINS 64
#endif

// native vector type: __builtin_nontemporal_load needs this, not HIP_vector_type
typedef float floatx4 __attribute__((ext_vector_type(4)));

__global__ __launch_bounds__(256) void cesl_kernel(
    const float* __restrict__ preds,
    const int* __restrict__ targets,
    float* __restrict__ out,
    int n_rows)
{
    const int lane        = threadIdx.x & 63;
    const int waveInBlock = threadIdx.x >> 6;
    const int wavesPerBlk = blockDim.x >> 6;
    const int globalWave  = blockIdx.x * wavesPerBlk + waveInBlock;
    const int totalWaves  = gridDim.x * wavesPerBlk;

    // 16 lanes per row, 4 consecutive cols per lane: one dwordx4/lane,
    // 64 lanes cover 4 contiguous rows = up to 1 KB coalesced per wave-iter.
    const int group   = lane >> 4;         // row within the 4-row chunk
    const int colBase = (lane & 15) * 4;   // starting column for this lane

    float acc = 0.0f;  // sum of log2(arg); loss = -ln2 * acc / n

    const int nChunks = n_rows >> 2;
    for (int chunk = globalWave; chunk < nChunks; chunk += totalWaves) {
        const int row = chunk * 4 + group;
        const int2 tg = *reinterpret_cast<const int2*>(targets + (size_t)row * 2);
        int t = tg.x;
        t = (t < 0) ? 0 : (t > T_BINS - 1 ? T_BINS - 1 : t);
        const bool ev = (tg.y != 0);

        if (colBase <= t) {   // chunks fully past t contribute 0: skip the load
            const floatx4 p4 = __builtin_nontemporal_load(
                reinterpret_cast<const floatx4*>(preds + (size_t)row * T_BINS + colBase));
            float prod = 1.0f;
#pragma unroll
            for (int k = 0; k < 4; ++k) {
                const int col = colBase + k;
                const float h = fminf(fmaxf(p4[k], 1e-9f), 0.99999994f);
                float arg = 1.0f - h;
                arg = (ev && col == t) ? h : arg;   // event at target bin: h
                arg = (col > t) ? 1.0f : arg;       // past target: contributes 0
                prod *= arg;
            }
            acc += __log2f(prod);
        }
    }

    // tail rows (n_rows % 4) — empty for N=1e6
    const int tailStart = nChunks * 4;
    if (globalWave == 0 && tailStart < n_rows) {
        for (int row = tailStart + group; row < n_rows; row += 4) {
            const int2 tg = *reinterpret_cast<const int2*>(targets + (size_t)row * 2);
            int t = tg.x;
            t = (t < 0) ? 0 : (t > T_BINS - 1 ? T_BINS - 1 : t);
            const bool ev = (tg.y != 0);
            if (colBase <= t) {
                const floatx4 p4 = *reinterpret_cast<const floatx4*>(
                    preds + (size_t)row * T_BINS + colBase);
                float prod = 1.0f;
#pragma unroll
                for (int k = 0; k < 4; ++k) {
                    const int col = colBase + k;
                    const float h = fminf(fmaxf(p4[k], 1e-9f), 0.99999994f);
                    float arg = 1.0f - h;
                    arg = (ev && col == t) ? h : arg;
                    arg = (col > t) ? 1.0f : arg;
                    prod *= arg;
                }
                acc += __log2f(prod);
            }
        }
    }

    // wave reduction (64 lanes)
#pragma unroll
    for (int off = 32; off > 0; off >>= 1)
        acc += __shfl_xor(acc, off, 64);

    __shared__ float waveSums[8];
    if (lane == 0) waveSums[waveInBlock] = acc;
    __syncthreads();
    if (threadIdx.x == 0) {
        float s = 0.0f;
        for (int w = 0; w < wavesPerBlk; ++w) s += waveSums[w];
        // loss = -ln2 * sum(log2(arg)) / n
        atomicAdd(out, s * (-0.69314718055994530942f / (float)n_rows));
    }
}

extern "C" void kernel_launch(void* const* d_in, const int* in_sizes, int n_in,
                              void* d_out, int out_size, void* d_ws, size_t ws_size,
                              hipStream_t stream) {
    const float* preds  = (const float*)d_in[0];
    const int* targets  = (const int*)d_in[1];
    float* out          = (float*)d_out;
    const int n_rows    = in_sizes[0] / T_BINS;

    (void)hipMemsetAsync(d_out, 0, sizeof(float), stream);

    const int blocks = 2048;   // 8 blocks/CU x 256 thr -> 32 waves/CU
    cesl_kernel<<<blocks, 256, 0, stream>>>(preds, targets, out, n_rows);
}